// Round 1
// baseline (2288.288 us; speedup 1.0000x reference)
//
#include <hip/hip_runtime.h>

#define N_NODES 100000
#define D 128
#define N_EDGES 600000
#define GR 8

// ---------- edge index dtype handling ----------
// Reference declares int64 edge indices, but harness convention says int32.
// Detect on device: if the data is int32, reading it as int64 produces values
// with nonzero high words (>= 2^32) almost surely within 64 samples.
__device__ __forceinline__ long long load_idx(const void* e, long long i, int is32) {
    if (is32) return (long long)((const int*)e)[i];
    return ((const long long*)e)[i];
}

__global__ void detect_kernel(const unsigned long long* __restrict__ e, int* __restrict__ flag) {
    if (threadIdx.x == 0 && blockIdx.x == 0) {
        int is32 = 0;
        for (int i = 0; i < 64; ++i) {
            if (e[i] > 0xFFFFFFFFull) { is32 = 1; break; }
        }
        *flag = is32;
    }
}

// ---------- tiny precompute: M = W @ weight_half, bt = b1@Wa + b2@Wb + bias ----------
__global__ void prep_M(const float* __restrict__ W, const float* __restrict__ weight,
                       int woff, float* __restrict__ M) {
    int idx = blockIdx.x * blockDim.x + threadIdx.x;
    if (idx >= D * D) return;
    int i = idx >> 7, j = idx & (D - 1);
    float a = 0.f;
    for (int k = 0; k < D; ++k) a += W[i * D + k] * weight[(woff + k) * D + j];
    M[idx] = a;
}

__global__ void prep_bt(const float* __restrict__ b1, const float* __restrict__ b2,
                        const float* __restrict__ weight, const float* __restrict__ bias,
                        float* __restrict__ bt) {
    int j = threadIdx.x;
    if (j >= D) return;
    float a = bias[j];
    for (int k = 0; k < D; ++k)
        a += b1[k] * weight[k * D + j] + b2[k] * weight[(D + k) * D + j];
    bt[j] = a;
}

// ---------- degree histogram (counts only; +1 self loop folded in finalize) ----------
__global__ void degree_kernel(const void* __restrict__ edges, const int* __restrict__ flag,
                              float* __restrict__ deg) {
    int is32 = *flag;
    int i = blockIdx.x * blockDim.x + threadIdx.x;
    if (i < N_EDGES) {
        long long d = load_idx(edges, (long long)N_EDGES + i, is32);
        atomicAdd(&deg[d], 1.0f);
    }
}

__global__ void finalize_deg(float* __restrict__ deg) {
    int i = blockIdx.x * blockDim.x + threadIdx.x;
    if (i < N_NODES) deg[i] = rsqrtf(deg[i] + 1.0f);   // store dinv
}

// ---------- s = x * dinv^2 (self-loop term) ----------
__global__ void init_s(const float* __restrict__ x, const float* __restrict__ dinv,
                       float* __restrict__ s) {
    long long t = (long long)blockIdx.x * blockDim.x + threadIdx.x;  // N*32 float4 slots
    long long row = t >> 5;
    if (row >= N_NODES) return;
    float di = dinv[row];
    float f = di * di;
    float4 v = ((const float4*)x)[t];
    v.x *= f; v.y *= f; v.z *= f; v.w *= f;
    ((float4*)s)[t] = v;
}

// ---------- edge scatter: s[dst] += coef * x[src], 32 lanes per edge ----------
__global__ void scatter_kernel(const void* __restrict__ edges, const int* __restrict__ flag,
                               const float* __restrict__ x, const float* __restrict__ dinv,
                               float* __restrict__ s) {
    long long t = (long long)blockIdx.x * blockDim.x + threadIdx.x;
    long long e = t >> 5;
    int c = (int)(t & 31);
    if (e >= N_EDGES) return;
    int is32 = *flag;
    long long si = load_idx(edges, e, is32);
    long long di = load_idx(edges, (long long)N_EDGES + e, is32);
    float coef = dinv[si] * dinv[di];
    float4 v = ((const float4*)(x + si * D))[c];
    float* sp = s + di * D + (long long)c * 4;
    atomicAdd(sp + 0, v.x * coef);
    atomicAdd(sp + 1, v.y * coef);
    atomicAdd(sp + 2, v.z * coef);
    atomicAdd(sp + 3, v.w * coef);
}

// ---------- dense: out (+)= s @ M (+ bt on first pass) ----------
__global__ void gemm_kernel(const float* __restrict__ s, const float* __restrict__ M,
                            const float* __restrict__ bt, float* __restrict__ out,
                            int accumulate) {
    __shared__ float srow[GR][D];
    int j = threadIdx.x;                       // 0..127
    long long r0 = (long long)blockIdx.x * GR;
    #pragma unroll
    for (int r = 0; r < GR; ++r) srow[r][j] = s[(r0 + r) * D + j];
    __syncthreads();
    float acc[GR];
    #pragma unroll
    for (int r = 0; r < GR; ++r) acc[r] = 0.f;
    for (int k = 0; k < D; ++k) {
        float m = M[k * D + j];
        #pragma unroll
        for (int r = 0; r < GR; ++r) acc[r] += srow[r][k] * m;
    }
    if (accumulate) {
        #pragma unroll
        for (int r = 0; r < GR; ++r) out[(r0 + r) * D + j] += acc[r];
    } else {
        float b = bt[j];
        #pragma unroll
        for (int r = 0; r < GR; ++r) out[(r0 + r) * D + j] = acc[r] + b;
    }
}

extern "C" void kernel_launch(void* const* d_in, const int* in_sizes, int n_in,
                              void* d_out, int out_size, void* d_ws, size_t ws_size,
                              hipStream_t stream) {
    const float* x      = (const float*)d_in[0];
    const void*  e_pos  = d_in[1];
    const void*  e_neg  = d_in[2];
    const float* W1     = (const float*)d_in[3];
    const float* b1     = (const float*)d_in[4];
    const float* W2     = (const float*)d_in[5];
    const float* b2     = (const float*)d_in[6];
    const float* weight = (const float*)d_in[7];
    const float* bias   = (const float*)d_in[8];
    float* out = (float*)d_out;

    // workspace layout (needs ~49.4 MiB)
    float* s    = (float*)d_ws;                  // N*D
    float* dinv = s + (size_t)N_NODES * D;       // N
    float* M1   = dinv + N_NODES;                // D*D
    float* M2   = M1 + D * D;                    // D*D
    float* bt   = M2 + D * D;                    // D
    int*   flag = (int*)(bt + D);

    detect_kernel<<<1, 64, 0, stream>>>((const unsigned long long*)e_pos, flag);
    prep_M<<<(D * D + 255) / 256, 256, 0, stream>>>(W1, weight, 0, M1);
    prep_M<<<(D * D + 255) / 256, 256, 0, stream>>>(W2, weight, D, M2);
    prep_bt<<<1, D, 0, stream>>>(b1, b2, weight, bias, bt);

    const int dgrid = (N_EDGES + 255) / 256;
    const int ngrid = (N_NODES + 255) / 256;
    const int igrid = (N_NODES * 32) / 256;          // exact: 12500
    const long long sthreads = (long long)N_EDGES * 32;
    const int sgrid = (int)((sthreads + 255) / 256); // 75000

    // ---- conv 1 (positive edges) ----
    hipMemsetAsync(dinv, 0, N_NODES * sizeof(float), stream);
    degree_kernel<<<dgrid, 256, 0, stream>>>(e_pos, flag, dinv);
    finalize_deg<<<ngrid, 256, 0, stream>>>(dinv);
    init_s<<<igrid, 256, 0, stream>>>(x, dinv, s);
    scatter_kernel<<<sgrid, 256, 0, stream>>>(e_pos, flag, x, dinv, s);
    gemm_kernel<<<N_NODES / GR, D, 0, stream>>>(s, M1, bt, out, 0);

    // ---- conv 2 (negative edges) ----
    hipMemsetAsync(dinv, 0, N_NODES * sizeof(float), stream);
    degree_kernel<<<dgrid, 256, 0, stream>>>(e_neg, flag, dinv);
    finalize_deg<<<ngrid, 256, 0, stream>>>(dinv);
    init_s<<<igrid, 256, 0, stream>>>(x, dinv, s);
    scatter_kernel<<<sgrid, 256, 0, stream>>>(e_neg, flag, x, dinv, s);
    gemm_kernel<<<N_NODES / GR, D, 0, stream>>>(s, M2, bt, out, 1);
}

// Round 2
// 428.328 us; speedup vs baseline: 5.3424x; 5.3424x over previous
//
#include <hip/hip_runtime.h>

#define N_NODES 100000
#define D 128
#define N_EDGES 600000
#define GR 8
#define SCAN_B 256
#define NBLK ((N_NODES + SCAN_B - 1) / SCAN_B)   // 391

// ---------- edge index dtype handling ----------
__device__ __forceinline__ long long load_idx(const void* e, long long i, int is32) {
    if (is32) return (long long)((const int*)e)[i];
    return ((const long long*)e)[i];
}

__global__ void detect_kernel(const unsigned long long* __restrict__ e, int* __restrict__ flag) {
    if (threadIdx.x == 0 && blockIdx.x == 0) {
        int is32 = 0;
        for (int i = 0; i < 64; ++i) {
            if (e[i] > 0xFFFFFFFFull) { is32 = 1; break; }
        }
        *flag = is32;
    }
}

// ---------- tiny precompute: M = W @ weight_half, bt = b1@Wa + b2@Wb + bias ----------
__global__ void prep_M(const float* __restrict__ W, const float* __restrict__ weight,
                       int woff, float* __restrict__ M) {
    int idx = blockIdx.x * blockDim.x + threadIdx.x;
    if (idx >= D * D) return;
    int i = idx >> 7, j = idx & (D - 1);
    float a = 0.f;
    for (int k = 0; k < D; ++k) a += W[i * D + k] * weight[(woff + k) * D + j];
    M[idx] = a;
}

__global__ void prep_bt(const float* __restrict__ b1, const float* __restrict__ b2,
                        const float* __restrict__ weight, const float* __restrict__ bias,
                        float* __restrict__ bt) {
    int j = threadIdx.x;
    if (j >= D) return;
    float a = bias[j];
    for (int k = 0; k < D; ++k)
        a += b1[k] * weight[k * D + j] + b2[k] * weight[(D + k) * D + j];
    bt[j] = a;
}

// ---------- degree histogram (int) ----------
__global__ void degree_int(const void* __restrict__ edges, const int* __restrict__ flag,
                           int* __restrict__ degi) {
    int i = blockIdx.x * blockDim.x + threadIdx.x;
    if (i < N_EDGES) {
        int is32 = *flag;
        long long d = load_idx(edges, (long long)N_EDGES + i, is32);
        atomicAdd(&degi[d], 1);
    }
}

__global__ void make_dinv(const int* __restrict__ degi, float* __restrict__ dinv) {
    int i = blockIdx.x * blockDim.x + threadIdx.x;
    if (i < N_NODES) dinv[i] = rsqrtf((float)degi[i] + 1.0f);
}

// ---------- exclusive scan (3 kernels) ----------
__global__ void scan_pass1(const int* __restrict__ degi, int* __restrict__ bsum) {
    __shared__ int sm[SCAN_B];
    int i = blockIdx.x * SCAN_B + threadIdx.x;
    sm[threadIdx.x] = (i < N_NODES) ? degi[i] : 0;
    __syncthreads();
    for (int s = SCAN_B / 2; s > 0; s >>= 1) {
        if (threadIdx.x < s) sm[threadIdx.x] += sm[threadIdx.x + s];
        __syncthreads();
    }
    if (threadIdx.x == 0) bsum[blockIdx.x] = sm[0];
}

__global__ void scan_pass2(int* __restrict__ bsum) {   // single block of 512
    __shared__ int sm[512];
    int t = threadIdx.x;
    int v = (t < NBLK) ? bsum[t] : 0;
    sm[t] = v;
    __syncthreads();
    for (int ofs = 1; ofs < 512; ofs <<= 1) {
        int add = (t >= ofs) ? sm[t - ofs] : 0;
        __syncthreads();
        sm[t] += add;
        __syncthreads();
    }
    if (t < NBLK) bsum[t] = sm[t] - v;   // exclusive
}

__global__ void scan_pass3(const int* __restrict__ degi, const int* __restrict__ bsum,
                           int* __restrict__ off) {
    __shared__ int sm[SCAN_B];
    int i = blockIdx.x * SCAN_B + threadIdx.x;
    int v = (i < N_NODES) ? degi[i] : 0;
    sm[threadIdx.x] = v;
    __syncthreads();
    for (int ofs = 1; ofs < SCAN_B; ofs <<= 1) {
        int add = (threadIdx.x >= ofs) ? sm[threadIdx.x - ofs] : 0;
        __syncthreads();
        sm[threadIdx.x] += add;
        __syncthreads();
    }
    int excl = sm[threadIdx.x] - v + bsum[blockIdx.x];
    if (i < N_NODES) off[i] = excl;
    if (i == N_NODES - 1) off[N_NODES] = excl + v;   // total = E
}

// ---------- CSR fill ----------
__global__ void csr_fill(const void* __restrict__ edges, const int* __restrict__ flag,
                         const int* __restrict__ off, int* __restrict__ cnt,
                         int* __restrict__ csr_src) {
    int i = blockIdx.x * blockDim.x + threadIdx.x;
    if (i >= N_EDGES) return;
    int is32 = *flag;
    int si = (int)load_idx(edges, i, is32);
    int di = (int)load_idx(edges, (long long)N_EDGES + i, is32);
    int pos = off[di] + atomicAdd(&cnt[di], 1);
    csr_src[pos] = si;
}

// ---------- gather: s[n] = x[n]*dinv[n]^2 + sum_e coef * x[src_e]  (32 lanes/node) ----------
__global__ void gather_kernel(const int* __restrict__ off, const int* __restrict__ csr_src,
                              const float* __restrict__ x, const float* __restrict__ dinv,
                              float* __restrict__ s) {
    long long t = (long long)blockIdx.x * blockDim.x + threadIdx.x;
    long long n = t >> 5;
    int c = (int)(t & 31);
    if (n >= N_NODES) return;
    float dn = dinv[n];
    float f = dn * dn;
    float4 acc = ((const float4*)x)[n * 32 + c];
    acc.x *= f; acc.y *= f; acc.z *= f; acc.w *= f;
    int e0 = off[n], e1 = off[n + 1];
    for (int e = e0; e < e1; ++e) {
        int si = csr_src[e];
        float coef = dinv[si] * dn;
        float4 v = ((const float4*)x)[(long long)si * 32 + c];
        acc.x += coef * v.x; acc.y += coef * v.y;
        acc.z += coef * v.z; acc.w += coef * v.w;
    }
    ((float4*)s)[n * 32 + c] = acc;
}

// ---------- dense: out (+)= s @ M (+ bt on first pass) ----------
__global__ void gemm_kernel(const float* __restrict__ s, const float* __restrict__ M,
                            const float* __restrict__ bt, float* __restrict__ out,
                            int accumulate) {
    __shared__ float srow[GR][D];
    int j = threadIdx.x;                       // 0..127
    long long r0 = (long long)blockIdx.x * GR;
    #pragma unroll
    for (int r = 0; r < GR; ++r) srow[r][j] = s[(r0 + r) * D + j];
    __syncthreads();
    float acc[GR];
    #pragma unroll
    for (int r = 0; r < GR; ++r) acc[r] = 0.f;
    for (int k = 0; k < D; ++k) {
        float m = M[k * D + j];
        #pragma unroll
        for (int r = 0; r < GR; ++r) acc[r] += srow[r][k] * m;
    }
    if (accumulate) {
        #pragma unroll
        for (int r = 0; r < GR; ++r) out[(r0 + r) * D + j] += acc[r];
    } else {
        float b = bt[j];
        #pragma unroll
        for (int r = 0; r < GR; ++r) out[(r0 + r) * D + j] = acc[r] + b;
    }
}

extern "C" void kernel_launch(void* const* d_in, const int* in_sizes, int n_in,
                              void* d_out, int out_size, void* d_ws, size_t ws_size,
                              hipStream_t stream) {
    const float* x      = (const float*)d_in[0];
    const void*  e_pos  = d_in[1];
    const void*  e_neg  = d_in[2];
    const float* W1     = (const float*)d_in[3];
    const float* b1     = (const float*)d_in[4];
    const float* W2     = (const float*)d_in[5];
    const float* b2     = (const float*)d_in[6];
    const float* weight = (const float*)d_in[7];
    const float* bias   = (const float*)d_in[8];
    float* out = (float*)d_out;

    // ---- workspace layout (~56 MB) ----
    float* s    = (float*)d_ws;                     // N*D
    float* dinv = s + (size_t)N_NODES * D;          // N
    float* M1   = dinv + N_NODES;                   // D*D
    float* M2   = M1 + D * D;                       // D*D
    float* bt   = M2 + D * D;                       // D
    int*   flag = (int*)(bt + D);                   // 1
    int*   degi = flag + 1;                         // N   (zeroed per conv)
    int*   cnt  = degi + N_NODES;                   // N   (zeroed per conv, adjacent)
    int*   off  = cnt + N_NODES;                    // N+1
    int*   bsum = off + N_NODES + 1;                // NBLK
    int*   csr  = bsum + NBLK;                      // E

    detect_kernel<<<1, 64, 0, stream>>>((const unsigned long long*)e_pos, flag);
    prep_M<<<(D * D + 255) / 256, 256, 0, stream>>>(W1, weight, 0, M1);
    prep_M<<<(D * D + 255) / 256, 256, 0, stream>>>(W2, weight, D, M2);
    prep_bt<<<1, D, 0, stream>>>(b1, b2, weight, bias, bt);

    const int egrid = (N_EDGES + 255) / 256;
    const int ngrid = (N_NODES + 255) / 256;
    const int ggrid = (N_NODES * 32) / 256;          // 12500

    for (int conv = 0; conv < 2; ++conv) {
        const void* edges = conv ? e_neg : e_pos;
        const float* M = conv ? M2 : M1;
        // zero degi + cnt in one shot (adjacent)
        hipMemsetAsync(degi, 0, 2 * N_NODES * sizeof(int), stream);
        degree_int<<<egrid, 256, 0, stream>>>(edges, flag, degi);
        make_dinv<<<ngrid, 256, 0, stream>>>(degi, dinv);
        scan_pass1<<<NBLK, SCAN_B, 0, stream>>>(degi, bsum);
        scan_pass2<<<1, 512, 0, stream>>>(bsum);
        scan_pass3<<<NBLK, SCAN_B, 0, stream>>>(degi, bsum, off);
        csr_fill<<<egrid, 256, 0, stream>>>(edges, flag, off, cnt, csr);
        gather_kernel<<<ggrid, 256, 0, stream>>>(off, csr, x, dinv, s);
        gemm_kernel<<<N_NODES / GR, D, 0, stream>>>(s, M, bt, out, conv);
    }
}

// Round 4
// 306.376 us; speedup vs baseline: 7.4689x; 1.3980x over previous
//
#include <hip/hip_runtime.h>

#define N_NODES 100000
#define SPAD 100096                 // padded row count for s1/s2 (multiple of 128)
#define D 128
#define N_EDGES 600000
#define SCAN_B 256
#define NBLK ((N_NODES + SCAN_B - 1) / SCAN_B)   // 391

typedef __attribute__((ext_vector_type(8))) short bf16x8;
typedef __attribute__((ext_vector_type(4))) float f32x4;

__device__ __forceinline__ unsigned short f2bf(float f) {
    union { float f; unsigned u; } v; v.f = f;
    unsigned r = (v.u + 0x7fff + ((v.u >> 16) & 1)) >> 16;   // RNE
    return (unsigned short)r;
}

// ---------- edge index dtype handling ----------
__device__ __forceinline__ long long load_idx(const void* e, long long i, int is32) {
    if (is32) return (long long)((const int*)e)[i];
    return ((const long long*)e)[i];
}

__global__ void detect_kernel(const unsigned long long* __restrict__ e, int* __restrict__ flag) {
    if (threadIdx.x == 0 && blockIdx.x == 0) {
        int is32 = 0;
        for (int i = 0; i < 64; ++i) {
            if (e[i] > 0xFFFFFFFFull) { is32 = 1; break; }
        }
        *flag = is32;
    }
}

// ---------- Mt[j][k] bf16, j=out col (128), k=stacked contraction (256) ----------
__global__ void prep_Mt(const float* __restrict__ W1, const float* __restrict__ W2,
                        const float* __restrict__ weight, unsigned short* __restrict__ Mt) {
    int idx = blockIdx.x * blockDim.x + threadIdx.x;   // 128*256
    int j = idx >> 8, k = idx & 255;
    float a = 0.f;
    if (k < D) {
        for (int d = 0; d < D; ++d) a += W1[k * D + d] * weight[d * D + j];
    } else {
        for (int d = 0; d < D; ++d) a += W2[(k - D) * D + d] * weight[(D + d) * D + j];
    }
    Mt[j * 256 + k] = f2bf(a);
}

__global__ void prep_bt(const float* __restrict__ b1, const float* __restrict__ b2,
                        const float* __restrict__ weight, const float* __restrict__ bias,
                        float* __restrict__ bt) {
    int j = threadIdx.x;
    if (j >= D) return;
    float a = bias[j];
    for (int k = 0; k < D; ++k)
        a += b1[k] * weight[k * D + j] + b2[k] * weight[(D + k) * D + j];
    bt[j] = a;
}

// ---------- degree histogram (int) ----------
__global__ void degree_int(const void* __restrict__ edges, const int* __restrict__ flag,
                           int* __restrict__ degi) {
    int i = blockIdx.x * blockDim.x + threadIdx.x;
    if (i < N_EDGES) {
        int is32 = *flag;
        long long d = load_idx(edges, (long long)N_EDGES + i, is32);
        atomicAdd(&degi[d], 1);
    }
}

// ---------- scan pass1 (+ fused dinv computation) ----------
__global__ void scan_pass1(const int* __restrict__ degi, int* __restrict__ bsum,
                           float* __restrict__ dinv) {
    __shared__ int sm[SCAN_B];
    int i = blockIdx.x * SCAN_B + threadIdx.x;
    int v = (i < N_NODES) ? degi[i] : 0;
    if (i < N_NODES) dinv[i] = rsqrtf((float)v + 1.0f);
    sm[threadIdx.x] = v;
    __syncthreads();
    for (int s = SCAN_B / 2; s > 0; s >>= 1) {
        if (threadIdx.x < s) sm[threadIdx.x] += sm[threadIdx.x + s];
        __syncthreads();
    }
    if (threadIdx.x == 0) bsum[blockIdx.x] = sm[0];
}

__global__ void scan_pass2(int* __restrict__ bsum) {   // single block of 512
    __shared__ int sm[512];
    int t = threadIdx.x;
    int v = (t < NBLK) ? bsum[t] : 0;
    sm[t] = v;
    __syncthreads();
    for (int ofs = 1; ofs < 512; ofs <<= 1) {
        int add = (t >= ofs) ? sm[t - ofs] : 0;
        __syncthreads();
        sm[t] += add;
        __syncthreads();
    }
    if (t < NBLK) bsum[t] = sm[t] - v;   // exclusive
}

__global__ void scan_pass3(const int* __restrict__ degi, const int* __restrict__ bsum,
                           int* __restrict__ off) {
    __shared__ int sm[SCAN_B];
    int i = blockIdx.x * SCAN_B + threadIdx.x;
    int v = (i < N_NODES) ? degi[i] : 0;
    sm[threadIdx.x] = v;
    __syncthreads();
    for (int ofs = 1; ofs < SCAN_B; ofs <<= 1) {
        int add = (threadIdx.x >= ofs) ? sm[threadIdx.x - ofs] : 0;
        __syncthreads();
        sm[threadIdx.x] += add;
        __syncthreads();
    }
    int excl = sm[threadIdx.x] - v + bsum[blockIdx.x];
    if (i < N_NODES) off[i] = excl;
    if (i == N_NODES - 1) off[N_NODES] = excl + v;
}

// ---------- CSR fill ----------
__global__ void csr_fill(const void* __restrict__ edges, const int* __restrict__ flag,
                         const int* __restrict__ off, int* __restrict__ cnt,
                         int* __restrict__ csr_src) {
    int i = blockIdx.x * blockDim.x + threadIdx.x;
    if (i >= N_EDGES) return;
    int is32 = *flag;
    int si = (int)load_idx(edges, i, is32);
    int di = (int)load_idx(edges, (long long)N_EDGES + i, is32);
    int pos = off[di] + atomicAdd(&cnt[di], 1);
    csr_src[pos] = si;
}

// ---------- gather: s[n] = bf16( x[n]*dinv[n]^2 + sum_e coef*x[src_e] ) ----------
__global__ void gather_kernel(const int* __restrict__ off, const int* __restrict__ csr_src,
                              const float* __restrict__ x, const float* __restrict__ dinv,
                              unsigned short* __restrict__ s) {
    long long t = (long long)blockIdx.x * blockDim.x + threadIdx.x;
    long long n = t >> 5;
    int c = (int)(t & 31);
    if (n >= N_NODES) return;
    float dn = dinv[n];
    float f = dn * dn;
    float4 acc = ((const float4*)x)[n * 32 + c];
    acc.x *= f; acc.y *= f; acc.z *= f; acc.w *= f;
    int e0 = off[n], e1 = off[n + 1];
    for (int e = e0; e < e1; ++e) {
        int si = csr_src[e];
        float coef = dinv[si] * dn;
        float4 v = ((const float4*)x)[(long long)si * 32 + c];
        acc.x += coef * v.x; acc.y += coef * v.y;
        acc.z += coef * v.z; acc.w += coef * v.w;
    }
    ushort4 o;
    o.x = f2bf(acc.x); o.y = f2bf(acc.y); o.z = f2bf(acc.z); o.w = f2bf(acc.w);
    ((ushort4*)s)[n * 32 + c] = o;
}

// ---------- fused GEMM: out = [s1|s2] @ Mt^T + bt,  MFMA bf16 ----------
// block: 512 threads = 8 waves, 128 rows; wave w -> rows [blk*128 + 16w, +16)
__global__ __launch_bounds__(512) void gemm_fused(
    const unsigned short* __restrict__ s1, const unsigned short* __restrict__ s2,
    const unsigned short* __restrict__ Mt, const float* __restrict__ bt,
    float* __restrict__ out) {
    __shared__ unsigned short mlds[128][264];   // +8 pad: 528B row stride, 16B-aligned
    int t = threadIdx.x;
    // stage Mt [128][256] -> LDS (16B chunks)
    for (int c = t; c < 4096; c += 512) {
        int row = c >> 5;
        int kc = (c & 31) * 8;
        *(ulonglong2*)&mlds[row][kc] = *(const ulonglong2*)&Mt[row * 256 + kc];
    }
    __syncthreads();
    int wave = t >> 6, lane = t & 63;
    int r0 = blockIdx.x * 128 + wave * 16;
    long long arow = r0 + (lane & 15);
    int kofs = (lane >> 4) * 8;
    f32x4 acc[8];
    #pragma unroll
    for (int i = 0; i < 8; ++i) acc[i] = (f32x4){0.f, 0.f, 0.f, 0.f};
    #pragma unroll
    for (int ks = 0; ks < 8; ++ks) {
        const int kb = ks * 32;
        const unsigned short* srow = (kb < 128) ? (s1 + arow * D + kb)
                                                : (s2 + arow * D + (kb - 128));
        bf16x8 afrag = *(const bf16x8*)(srow + kofs);
        #pragma unroll
        for (int ct = 0; ct < 8; ++ct) {
            // FIX (R3 bug): index LDS with the FULL stacked k (kb + kofs),
            // not (kb & 127) — mlds holds all 256 k columns.
            bf16x8 bfrag = *(const bf16x8*)&mlds[ct * 16 + (lane & 15)][kb + kofs];
            acc[ct] = __builtin_amdgcn_mfma_f32_16x16x32_bf16(afrag, bfrag, acc[ct], 0, 0, 0);
        }
    }
    // C/D layout: col = lane&15, row = (lane>>4)*4 + reg
    int orow = r0 + (lane >> 4) * 4;
    #pragma unroll
    for (int ct = 0; ct < 8; ++ct) {
        int col = ct * 16 + (lane & 15);
        float b = bt[col];
        #pragma unroll
        for (int reg = 0; reg < 4; ++reg) {
            int row = orow + reg;
            if (row < N_NODES) out[(long long)row * D + col] = acc[ct][reg] + b;
        }
    }
}

extern "C" void kernel_launch(void* const* d_in, const int* in_sizes, int n_in,
                              void* d_out, int out_size, void* d_ws, size_t ws_size,
                              hipStream_t stream) {
    const float* x      = (const float*)d_in[0];
    const void*  e_pos  = d_in[1];
    const void*  e_neg  = d_in[2];
    const float* W1     = (const float*)d_in[3];
    const float* b1     = (const float*)d_in[4];
    const float* W2     = (const float*)d_in[5];
    const float* b2     = (const float*)d_in[6];
    const float* weight = (const float*)d_in[7];
    const float* bias   = (const float*)d_in[8];
    float* out = (float*)d_out;

    // ---- workspace layout (~55 MB) ----
    unsigned short* s1 = (unsigned short*)d_ws;          // SPAD*D bf16
    unsigned short* s2 = s1 + (size_t)SPAD * D;          // SPAD*D bf16
    unsigned short* Mt = s2 + (size_t)SPAD * D;          // 128*256 bf16
    float* bt   = (float*)(Mt + 128 * 256);              // D
    float* dinv = bt + D;                                // N
    int*   flag = (int*)(dinv + N_NODES);                // 1
    int*   degi = flag + 1;                              // N
    int*   cnt  = degi + N_NODES;                        // N (adjacent for joint memset)
    int*   off  = cnt + N_NODES;                         // N+1
    int*   bsum = off + N_NODES + 1;                     // 512
    int*   csr  = bsum + 512;                            // E

    detect_kernel<<<1, 64, 0, stream>>>((const unsigned long long*)e_pos, flag);
    prep_Mt<<<(128 * 256) / 256, 256, 0, stream>>>(W1, W2, weight, Mt);
    prep_bt<<<1, D, 0, stream>>>(b1, b2, weight, bias, bt);

    const int egrid = (N_EDGES + 255) / 256;
    const int ggrid = (N_NODES * 32) / 256;   // 12500

    for (int conv = 0; conv < 2; ++conv) {
        const void* edges = conv ? e_neg : e_pos;
        unsigned short* s = conv ? s2 : s1;
        hipMemsetAsync(degi, 0, 2 * N_NODES * sizeof(int), stream);
        degree_int<<<egrid, 256, 0, stream>>>(edges, flag, degi);
        scan_pass1<<<NBLK, SCAN_B, 0, stream>>>(degi, bsum, dinv);
        scan_pass2<<<1, 512, 0, stream>>>(bsum);
        scan_pass3<<<NBLK, SCAN_B, 0, stream>>>(degi, bsum, off);
        csr_fill<<<egrid, 256, 0, stream>>>(edges, flag, off, cnt, csr);
        gather_kernel<<<ggrid, 256, 0, stream>>>(off, csr, x, dinv, s);
    }
    gemm_fused<<<(SPAD / 128), 512, 0, stream>>>(s1, s2, Mt, bt, out);
}

// Round 5
// 248.581 us; speedup vs baseline: 9.2054x; 1.2325x over previous
//
#include <hip/hip_runtime.h>

#define N_NODES 100000
#define NT (2 * N_NODES)             // stacked nodes (conv1 then conv2)
#define SPAD 100096                  // padded row count for GEMM tiles
#define D 128
#define N_EDGES 600000
#define ET (2 * N_EDGES)
#define SCAN_B 256
#define NBLK2 ((NT + SCAN_B - 1) / SCAN_B)   // 782

typedef __attribute__((ext_vector_type(8))) short bf16x8;
typedef __attribute__((ext_vector_type(4))) float f32x4;

__device__ __forceinline__ unsigned short f2bf(float f) {
    union { float f; unsigned u; } v; v.f = f;
    unsigned r = (v.u + 0x7fff + ((v.u >> 16) & 1)) >> 16;   // RNE
    return (unsigned short)r;
}
__device__ __forceinline__ float bf2f(unsigned short h) {
    union { unsigned u; float f; } v; v.u = ((unsigned)h) << 16;
    return v.f;
}

// ---------- edge index dtype handling ----------
__device__ __forceinline__ long long load_idx(const void* e, long long i, int is32) {
    if (is32) return (long long)((const int*)e)[i];
    return ((const long long*)e)[i];
}

__global__ void detect_kernel(const unsigned long long* __restrict__ e, int* __restrict__ flag) {
    if (threadIdx.x == 0 && blockIdx.x == 0) {
        int is32 = 0;
        for (int i = 0; i < 64; ++i) {
            if (e[i] > 0xFFFFFFFFull) { is32 = 1; break; }
        }
        *flag = is32;
    }
}

// ---------- x (f32) -> xb (bf16) ----------
__global__ void x2bf_kernel(const float* __restrict__ x, unsigned short* __restrict__ xb) {
    long long t = (long long)blockIdx.x * blockDim.x + threadIdx.x;   // N*32 float4 slots
    if (t >= (long long)N_NODES * 32) return;
    float4 a = ((const float4*)x)[t];
    ((ushort4*)xb)[t] = make_ushort4(f2bf(a.x), f2bf(a.y), f2bf(a.z), f2bf(a.w));
}

// ---------- Mt[j][k] bf16, j=out col (128), k=stacked contraction (256) ----------
__global__ void prep_Mt(const float* __restrict__ W1, const float* __restrict__ W2,
                        const float* __restrict__ weight, unsigned short* __restrict__ Mt) {
    int idx = blockIdx.x * blockDim.x + threadIdx.x;   // 128*256
    int j = idx >> 8, k = idx & 255;
    float a = 0.f;
    if (k < D) {
        for (int d = 0; d < D; ++d) a += W1[k * D + d] * weight[d * D + j];
    } else {
        for (int d = 0; d < D; ++d) a += W2[(k - D) * D + d] * weight[(D + d) * D + j];
    }
    Mt[j * 256 + k] = f2bf(a);
}

__global__ void prep_bt(const float* __restrict__ b1, const float* __restrict__ b2,
                        const float* __restrict__ weight, const float* __restrict__ bias,
                        float* __restrict__ bt) {
    int j = threadIdx.x;
    if (j >= D) return;
    float a = bias[j];
    for (int k = 0; k < D; ++k)
        a += b1[k] * weight[k * D + j] + b2[k] * weight[(D + k) * D + j];
    bt[j] = a;
}

// ---------- degree histogram over both edge lists ----------
__global__ void degree_both(const void* __restrict__ ep, const void* __restrict__ en,
                            const int* __restrict__ flag, int* __restrict__ degi) {
    int i = blockIdx.x * blockDim.x + threadIdx.x;
    if (i >= ET) return;
    int is32 = *flag;
    int conv = (i >= N_EDGES);
    const void* e = conv ? en : ep;
    int j = conv ? i - N_EDGES : i;
    long long d = load_idx(e, (long long)N_EDGES + j, is32);
    atomicAdd(&degi[conv * N_NODES + (int)d], 1);
}

// ---------- scan pass1 over NT (+ fused dinv) ----------
__global__ void scan_pass1(const int* __restrict__ degi, int* __restrict__ bsum,
                           float* __restrict__ dinv) {
    __shared__ int sm[SCAN_B];
    int i = blockIdx.x * SCAN_B + threadIdx.x;
    int v = (i < NT) ? degi[i] : 0;
    if (i < NT) dinv[i] = rsqrtf((float)v + 1.0f);
    sm[threadIdx.x] = v;
    __syncthreads();
    for (int s = SCAN_B / 2; s > 0; s >>= 1) {
        if (threadIdx.x < s) sm[threadIdx.x] += sm[threadIdx.x + s];
        __syncthreads();
    }
    if (threadIdx.x == 0) bsum[blockIdx.x] = sm[0];
}

__global__ void scan_pass2(int* __restrict__ bsum) {   // single block of 1024
    __shared__ int sm[1024];
    int t = threadIdx.x;
    int v = (t < NBLK2) ? bsum[t] : 0;
    sm[t] = v;
    __syncthreads();
    for (int ofs = 1; ofs < 1024; ofs <<= 1) {
        int add = (t >= ofs) ? sm[t - ofs] : 0;
        __syncthreads();
        sm[t] += add;
        __syncthreads();
    }
    if (t < NBLK2) bsum[t] = sm[t] - v;   // exclusive
}

__global__ void scan_pass3(const int* __restrict__ degi, const int* __restrict__ bsum,
                           int* __restrict__ off) {
    __shared__ int sm[SCAN_B];
    int i = blockIdx.x * SCAN_B + threadIdx.x;
    int v = (i < NT) ? degi[i] : 0;
    sm[threadIdx.x] = v;
    __syncthreads();
    for (int ofs = 1; ofs < SCAN_B; ofs <<= 1) {
        int add = (threadIdx.x >= ofs) ? sm[threadIdx.x - ofs] : 0;
        __syncthreads();
        sm[threadIdx.x] += add;
        __syncthreads();
    }
    int excl = sm[threadIdx.x] - v + bsum[blockIdx.x];
    if (i < NT) off[i] = excl;
    if (i == NT - 1) off[NT] = excl + v;
}

// ---------- CSR fill (both convs), stores {src_row, coef} ----------
__global__ void csr_fill_both(const void* __restrict__ ep, const void* __restrict__ en,
                              const int* __restrict__ flag, const int* __restrict__ off,
                              int* __restrict__ cnt, const float* __restrict__ dinv,
                              int2* __restrict__ csr) {
    int i = blockIdx.x * blockDim.x + threadIdx.x;
    if (i >= ET) return;
    int is32 = *flag;
    int conv = (i >= N_EDGES);
    const void* e = conv ? en : ep;
    int j = conv ? i - N_EDGES : i;
    int si = (int)load_idx(e, j, is32);
    int di = (int)load_idx(e, (long long)N_EDGES + j, is32);
    int g = conv * N_NODES;
    int node = g + di;
    int pos = off[node] + atomicAdd(&cnt[node], 1);
    float coef = dinv[g + si] * dinv[node];
    csr[pos] = make_int2(si, __float_as_int(coef));
}

// ---------- gather over both convs: 16 lanes/node, 8 cols/lane ----------
template <int XBF>
__global__ void gather_both(const int* __restrict__ off, const int2* __restrict__ csr,
                            const void* __restrict__ xv, const float* __restrict__ dinv,
                            unsigned short* __restrict__ s) {
    long long t = (long long)blockIdx.x * blockDim.x + threadIdx.x;
    long long n = t >> 4;
    int c = (int)(t & 15);
    if (n >= NT) return;
    long long xrow = (n >= N_NODES) ? n - N_NODES : n;
    float dn = dinv[n];
    float f = dn * dn;
    float acc[8];
    if (XBF) {
        const unsigned short* xb = (const unsigned short*)xv;
        bf16x8 v = ((const bf16x8*)xb)[xrow * 16 + c];
        #pragma unroll
        for (int j = 0; j < 8; ++j) acc[j] = bf2f((unsigned short)v[j]) * f;
    } else {
        const float* x = (const float*)xv;
        float4 a = ((const float4*)x)[xrow * 32 + c * 2];
        float4 b = ((const float4*)x)[xrow * 32 + c * 2 + 1];
        acc[0] = a.x * f; acc[1] = a.y * f; acc[2] = a.z * f; acc[3] = a.w * f;
        acc[4] = b.x * f; acc[5] = b.y * f; acc[6] = b.z * f; acc[7] = b.w * f;
    }
    int e0 = off[n], e1 = off[n + 1];
    for (int e = e0; e < e1; ++e) {
        int2 sc = csr[e];
        float coef = __int_as_float(sc.y);
        if (XBF) {
            const unsigned short* xb = (const unsigned short*)xv;
            bf16x8 v = ((const bf16x8*)xb)[(long long)sc.x * 16 + c];
            #pragma unroll
            for (int j = 0; j < 8; ++j) acc[j] += coef * bf2f((unsigned short)v[j]);
        } else {
            const float* x = (const float*)xv;
            float4 a = ((const float4*)x)[(long long)sc.x * 32 + c * 2];
            float4 b = ((const float4*)x)[(long long)sc.x * 32 + c * 2 + 1];
            acc[0] += coef * a.x; acc[1] += coef * a.y; acc[2] += coef * a.z; acc[3] += coef * a.w;
            acc[4] += coef * b.x; acc[5] += coef * b.y; acc[6] += coef * b.z; acc[7] += coef * b.w;
        }
    }
    ushort4 o0 = make_ushort4(f2bf(acc[0]), f2bf(acc[1]), f2bf(acc[2]), f2bf(acc[3]));
    ushort4 o1 = make_ushort4(f2bf(acc[4]), f2bf(acc[5]), f2bf(acc[6]), f2bf(acc[7]));
    ((ushort4*)s)[n * 32 + c * 2]     = o0;
    ((ushort4*)s)[n * 32 + c * 2 + 1] = o1;
}

// ---------- fused GEMM: out = [s1|s2] @ Mt^T + bt,  MFMA bf16 ----------
__global__ __launch_bounds__(512) void gemm_fused(
    const unsigned short* __restrict__ s1, const unsigned short* __restrict__ s2,
    const unsigned short* __restrict__ Mt, const float* __restrict__ bt,
    float* __restrict__ out) {
    __shared__ unsigned short mlds[128][264];   // +8 pad
    int t = threadIdx.x;
    for (int c = t; c < 4096; c += 512) {
        int row = c >> 5;
        int kc = (c & 31) * 8;
        *(ulonglong2*)&mlds[row][kc] = *(const ulonglong2*)&Mt[row * 256 + kc];
    }
    __syncthreads();
    int wave = t >> 6, lane = t & 63;
    int r0 = blockIdx.x * 128 + wave * 16;
    long long arow = r0 + (lane & 15);
    int kofs = (lane >> 4) * 8;
    f32x4 acc[8];
    #pragma unroll
    for (int i = 0; i < 8; ++i) acc[i] = (f32x4){0.f, 0.f, 0.f, 0.f};
    #pragma unroll
    for (int ks = 0; ks < 8; ++ks) {
        const int kb = ks * 32;
        const unsigned short* srow = (kb < 128) ? (s1 + arow * D + kb)
                                                : (s2 + arow * D + (kb - 128));
        bf16x8 afrag = *(const bf16x8*)(srow + kofs);
        #pragma unroll
        for (int ct = 0; ct < 8; ++ct) {
            bf16x8 bfrag = *(const bf16x8*)&mlds[ct * 16 + (lane & 15)][kb + kofs];
            acc[ct] = __builtin_amdgcn_mfma_f32_16x16x32_bf16(afrag, bfrag, acc[ct], 0, 0, 0);
        }
    }
    int orow = r0 + (lane >> 4) * 4;
    #pragma unroll
    for (int ct = 0; ct < 8; ++ct) {
        int col = ct * 16 + (lane & 15);
        float b = bt[col];
        #pragma unroll
        for (int reg = 0; reg < 4; ++reg) {
            int row = orow + reg;
            if (row < N_NODES) out[(long long)row * D + col] = acc[ct][reg] + b;
        }
    }
}

extern "C" void kernel_launch(void* const* d_in, const int* in_sizes, int n_in,
                              void* d_out, int out_size, void* d_ws, size_t ws_size,
                              hipStream_t stream) {
    const float* x      = (const float*)d_in[0];
    const void*  e_pos  = d_in[1];
    const void*  e_neg  = d_in[2];
    const float* W1     = (const float*)d_in[3];
    const float* b1     = (const float*)d_in[4];
    const float* W2     = (const float*)d_in[5];
    const float* b2     = (const float*)d_in[6];
    const float* weight = (const float*)d_in[7];
    const float* bias   = (const float*)d_in[8];
    float* out = (float*)d_out;

    // ---- workspace layout ----
    // s: (NT+128) rows bf16 (tail pad so GEMM's s2 reads stay in-bounds)
    unsigned short* s  = (unsigned short*)d_ws;                 // (NT+128)*D
    unsigned short* Mt = s + (size_t)(NT + 128) * D;            // 128*256
    float* bt   = (float*)(Mt + 128 * 256);                     // D
    float* dinv = bt + D;                                       // NT
    int*   flag = (int*)(dinv + NT);                            // pad to 4 ints
    int*   degi = flag + 4;                                     // NT
    int*   cnt  = degi + NT;                                    // NT
    int*   off  = cnt + NT;                                     // NT+4 (pad)
    int*   bsum = off + NT + 4;                                 // 1024
    int2*  csr  = (int2*)(bsum + 1024);                         // ET
    unsigned short* xb = (unsigned short*)(csr + ET);           // N*D (optional)

    size_t need_bf16 = (size_t)((char*)(xb + (size_t)N_NODES * D) - (char*)d_ws);
    const int use_bf16_x = (ws_size >= need_bf16);

    unsigned short* s1 = s;
    unsigned short* s2 = s + (size_t)N_NODES * D;

    detect_kernel<<<1, 64, 0, stream>>>((const unsigned long long*)e_pos, flag);
    if (use_bf16_x) x2bf_kernel<<<12500, 256, 0, stream>>>(x, xb);
    prep_Mt<<<(128 * 256) / 256, 256, 0, stream>>>(W1, W2, weight, Mt);
    prep_bt<<<1, D, 0, stream>>>(b1, b2, weight, bias, bt);

    hipMemsetAsync(degi, 0, 2 * NT * sizeof(int), stream);   // degi + cnt (adjacent)
    const int egrid = (ET + 255) / 256;                      // 4688
    degree_both<<<egrid, 256, 0, stream>>>(e_pos, e_neg, flag, degi);
    scan_pass1<<<NBLK2, SCAN_B, 0, stream>>>(degi, bsum, dinv);
    scan_pass2<<<1, 1024, 0, stream>>>(bsum);
    scan_pass3<<<NBLK2, SCAN_B, 0, stream>>>(degi, bsum, off);
    csr_fill_both<<<egrid, 256, 0, stream>>>(e_pos, e_neg, flag, off, cnt, dinv, csr);

    const int ggrid = (NT * 16) / 256;   // 12500 exact
    if (use_bf16_x)
        gather_both<1><<<ggrid, 256, 0, stream>>>(off, csr, xb, dinv, s);
    else
        gather_both<0><<<ggrid, 256, 0, stream>>>(off, csr, x, dinv, s);

    gemm_fused<<<(SPAD / 128), 512, 0, stream>>>(s1, s2, Mt, bt, out);
}

// Round 6
// 240.551 us; speedup vs baseline: 9.5127x; 1.0334x over previous
//
#include <hip/hip_runtime.h>

#define N_NODES 100000
#define NT (2 * N_NODES)             // stacked nodes (conv1 then conv2)
#define D 128
#define N_EDGES 600000
#define ET (2 * N_EDGES)
#define SCAN_B 256
#define NBLK2 ((NT + SCAN_B - 1) / SCAN_B)   // 782
#define FBLK ((N_NODES + 127) / 128)         // 782 fused blocks

typedef __attribute__((ext_vector_type(8))) short bf16x8;
typedef __attribute__((ext_vector_type(4))) float f32x4;

__device__ __forceinline__ unsigned short f2bf(float f) {
    union { float f; unsigned u; } v; v.f = f;
    unsigned r = (v.u + 0x7fff + ((v.u >> 16) & 1)) >> 16;   // RNE
    return (unsigned short)r;
}
__device__ __forceinline__ float bf2f(unsigned short h) {
    union { unsigned u; float f; } v; v.u = ((unsigned)h) << 16;
    return v.f;
}

// ---------- edge index dtype handling ----------
__device__ __forceinline__ long long load_idx(const void* e, long long i, int is32) {
    if (is32) return (long long)((const int*)e)[i];
    return ((const long long*)e)[i];
}

__global__ void detect_kernel(const unsigned long long* __restrict__ e, int* __restrict__ flag) {
    if (threadIdx.x == 0 && blockIdx.x == 0) {
        int is32 = 0;
        for (int i = 0; i < 64; ++i) {
            if (e[i] > 0xFFFFFFFFull) { is32 = 1; break; }
        }
        *flag = is32;
    }
}

// ---------- x (f32) -> xb (bf16) ----------
__global__ void x2bf_kernel(const float* __restrict__ x, unsigned short* __restrict__ xb) {
    long long t = (long long)blockIdx.x * blockDim.x + threadIdx.x;   // N*32 float4 slots
    if (t >= (long long)N_NODES * 32) return;
    float4 a = ((const float4*)x)[t];
    ((ushort4*)xb)[t] = make_ushort4(f2bf(a.x), f2bf(a.y), f2bf(a.z), f2bf(a.w));
}

// ---------- Mt[j][k] bf16, j=out col (128), k=stacked contraction (256) ----------
__global__ void prep_Mt(const float* __restrict__ W1, const float* __restrict__ W2,
                        const float* __restrict__ weight, unsigned short* __restrict__ Mt) {
    int idx = blockIdx.x * blockDim.x + threadIdx.x;   // 128*256
    int j = idx >> 8, k = idx & 255;
    float a = 0.f;
    if (k < D) {
        for (int d = 0; d < D; ++d) a += W1[k * D + d] * weight[d * D + j];
    } else {
        for (int d = 0; d < D; ++d) a += W2[(k - D) * D + d] * weight[(D + d) * D + j];
    }
    Mt[j * 256 + k] = f2bf(a);
}

__global__ void prep_bt(const float* __restrict__ b1, const float* __restrict__ b2,
                        const float* __restrict__ weight, const float* __restrict__ bias,
                        float* __restrict__ bt) {
    int j = threadIdx.x;
    if (j >= D) return;
    float a = bias[j];
    for (int k = 0; k < D; ++k)
        a += b1[k] * weight[k * D + j] + b2[k] * weight[(D + k) * D + j];
    bt[j] = a;
}

// ---------- degree histogram over both edge lists ----------
__global__ void degree_both(const void* __restrict__ ep, const void* __restrict__ en,
                            const int* __restrict__ flag, int* __restrict__ degi) {
    int i = blockIdx.x * blockDim.x + threadIdx.x;
    if (i >= ET) return;
    int is32 = *flag;
    int conv = (i >= N_EDGES);
    const void* e = conv ? en : ep;
    int j = conv ? i - N_EDGES : i;
    long long d = load_idx(e, (long long)N_EDGES + j, is32);
    atomicAdd(&degi[conv * N_NODES + (int)d], 1);
}

// ---------- scan pass1 over NT (+ fused dinv) ----------
__global__ void scan_pass1(const int* __restrict__ degi, int* __restrict__ bsum,
                           float* __restrict__ dinv) {
    __shared__ int sm[SCAN_B];
    int i = blockIdx.x * SCAN_B + threadIdx.x;
    int v = (i < NT) ? degi[i] : 0;
    if (i < NT) dinv[i] = rsqrtf((float)v + 1.0f);
    sm[threadIdx.x] = v;
    __syncthreads();
    for (int s = SCAN_B / 2; s > 0; s >>= 1) {
        if (threadIdx.x < s) sm[threadIdx.x] += sm[threadIdx.x + s];
        __syncthreads();
    }
    if (threadIdx.x == 0) bsum[blockIdx.x] = sm[0];
}

__global__ void scan_pass2(int* __restrict__ bsum) {   // single block of 1024
    __shared__ int sm[1024];
    int t = threadIdx.x;
    int v = (t < NBLK2) ? bsum[t] : 0;
    sm[t] = v;
    __syncthreads();
    for (int ofs = 1; ofs < 1024; ofs <<= 1) {
        int add = (t >= ofs) ? sm[t - ofs] : 0;
        __syncthreads();
        sm[t] += add;
        __syncthreads();
    }
    if (t < NBLK2) bsum[t] = sm[t] - v;   // exclusive
}

__global__ void scan_pass3(const int* __restrict__ degi, const int* __restrict__ bsum,
                           int* __restrict__ off) {
    __shared__ int sm[SCAN_B];
    int i = blockIdx.x * SCAN_B + threadIdx.x;
    int v = (i < NT) ? degi[i] : 0;
    sm[threadIdx.x] = v;
    __syncthreads();
    for (int ofs = 1; ofs < SCAN_B; ofs <<= 1) {
        int add = (threadIdx.x >= ofs) ? sm[threadIdx.x - ofs] : 0;
        __syncthreads();
        sm[threadIdx.x] += add;
        __syncthreads();
    }
    int excl = sm[threadIdx.x] - v + bsum[blockIdx.x];
    if (i < NT) off[i] = excl;
    if (i == NT - 1) off[NT] = excl + v;
}

// ---------- CSR fill (both convs), stores {src_row, coef}; degi used as countdown ----------
__global__ void csr_fill_both(const void* __restrict__ ep, const void* __restrict__ en,
                              const int* __restrict__ flag, const int* __restrict__ off,
                              int* __restrict__ degi, const float* __restrict__ dinv,
                              int2* __restrict__ csr) {
    int i = blockIdx.x * blockDim.x + threadIdx.x;
    if (i >= ET) return;
    int is32 = *flag;
    int conv = (i >= N_EDGES);
    const void* e = conv ? en : ep;
    int j = conv ? i - N_EDGES : i;
    int si = (int)load_idx(e, j, is32);
    int di = (int)load_idx(e, (long long)N_EDGES + j, is32);
    int g = conv * N_NODES;
    int node = g + di;
    int pos = off[node] + atomicSub(&degi[node], 1) - 1;   // countdown: positions deg-1..0
    float coef = dinv[g + si] * dinv[node];
    csr[pos] = make_int2(si, __float_as_int(coef));
}

// ---------- fused gather + GEMM ----------
// 512 threads = 8 waves; wave w owns output rows [blk*128 + 16w, +16).
// Lane l (rl = l&15, q = l>>4) gathers rows (conv, blk*128+16w+rl), cols
// q*8 + {0,32,64,96} of each conv row — exactly its 8 MFMA A-fragments.
__global__ __launch_bounds__(512) void fused_gather_gemm(
    const int* __restrict__ off, const int2* __restrict__ csr,
    const unsigned short* __restrict__ xb, const float* __restrict__ dinv,
    const unsigned short* __restrict__ Mt, const float* __restrict__ bt,
    float* __restrict__ out) {
    __shared__ unsigned short mlds[128][264];   // +8 pad: 2-way bank alias only (free)
    int t = threadIdx.x;
    for (int c = t; c < 4096; c += 512) {
        int row = c >> 5;
        int kc = (c & 31) * 8;
        *(ulonglong2*)&mlds[row][kc] = *(const ulonglong2*)&Mt[row * 256 + kc];
    }
    __syncthreads();

    int wave = t >> 6, lane = t & 63;
    int rl = lane & 15, q = lane >> 4;
    int gr = blockIdx.x * 128 + wave * 16 + rl;          // gathered row
    const bool valid = gr < N_NODES;

    bf16x8 af[8];
    #pragma unroll
    for (int conv = 0; conv < 2; ++conv) {
        float acc[4][8];
        if (valid) {
            int n = conv * N_NODES + gr;
            float dn = dinv[n];
            float f = dn * dn;
            const unsigned short* xr = xb + (size_t)gr * D + q * 8;
            #pragma unroll
            for (int m = 0; m < 4; ++m) {
                bf16x8 v = *(const bf16x8*)(xr + m * 32);
                #pragma unroll
                for (int j = 0; j < 8; ++j) acc[m][j] = bf2f((unsigned short)v[j]) * f;
            }
            int e0 = off[n], e1 = off[n + 1];
            for (int e = e0; e < e1; ++e) {
                int2 sc = csr[e];
                float coef = __int_as_float(sc.y);
                const unsigned short* xs = xb + (size_t)sc.x * D + q * 8;
                #pragma unroll
                for (int m = 0; m < 4; ++m) {
                    bf16x8 v = *(const bf16x8*)(xs + m * 32);
                    #pragma unroll
                    for (int j = 0; j < 8; ++j) acc[m][j] += coef * bf2f((unsigned short)v[j]);
                }
            }
        } else {
            #pragma unroll
            for (int m = 0; m < 4; ++m)
                #pragma unroll
                for (int j = 0; j < 8; ++j) acc[m][j] = 0.f;
        }
        #pragma unroll
        for (int m = 0; m < 4; ++m) {
            bf16x8 a;
            #pragma unroll
            for (int j = 0; j < 8; ++j) a[j] = (short)f2bf(acc[m][j]);
            af[conv * 4 + m] = a;
        }
    }

    f32x4 C[8];
    #pragma unroll
    for (int i = 0; i < 8; ++i) C[i] = (f32x4){0.f, 0.f, 0.f, 0.f};
    #pragma unroll
    for (int ks = 0; ks < 8; ++ks) {
        bf16x8 afr = af[ks];          // ks 0..3 -> conv1 k-blocks, 4..7 -> conv2
        #pragma unroll
        for (int ct = 0; ct < 8; ++ct) {
            bf16x8 bfr = *(const bf16x8*)&mlds[ct * 16 + rl][ks * 32 + q * 8];
            C[ct] = __builtin_amdgcn_mfma_f32_16x16x32_bf16(afr, bfr, C[ct], 0, 0, 0);
        }
    }

    // C/D layout: col = lane&15, row = (lane>>4)*4 + reg
    int orow = blockIdx.x * 128 + wave * 16 + q * 4;
    #pragma unroll
    for (int ct = 0; ct < 8; ++ct) {
        int col = ct * 16 + rl;
        float b = bt[col];
        #pragma unroll
        for (int reg = 0; reg < 4; ++reg) {
            int row = orow + reg;
            if (row < N_NODES) out[(long long)row * D + col] = C[ct][reg] + b;
        }
    }
}

extern "C" void kernel_launch(void* const* d_in, const int* in_sizes, int n_in,
                              void* d_out, int out_size, void* d_ws, size_t ws_size,
                              hipStream_t stream) {
    const float* x      = (const float*)d_in[0];
    const void*  e_pos  = d_in[1];
    const void*  e_neg  = d_in[2];
    const float* W1     = (const float*)d_in[3];
    const float* b1     = (const float*)d_in[4];
    const float* W2     = (const float*)d_in[5];
    const float* b2     = (const float*)d_in[6];
    const float* weight = (const float*)d_in[7];
    const float* bias   = (const float*)d_in[8];
    float* out = (float*)d_out;

    // ---- workspace layout (~38 MB) ----
    unsigned short* xb = (unsigned short*)d_ws;          // N*D bf16
    unsigned short* Mt = xb + (size_t)N_NODES * D;       // 128*256
    float* bt   = (float*)(Mt + 128 * 256);              // D
    float* dinv = bt + D;                                // NT
    int*   flag = (int*)(dinv + NT);                     // pad to 4 ints
    int*   degi = flag + 4;                              // NT
    int*   off  = degi + NT;                             // NT+4 (pad)
    int*   bsum = off + NT + 4;                          // 1024
    int2*  csr  = (int2*)(bsum + 1024);                  // ET

    detect_kernel<<<1, 64, 0, stream>>>((const unsigned long long*)e_pos, flag);
    x2bf_kernel<<<12500, 256, 0, stream>>>(x, xb);
    prep_Mt<<<(128 * 256) / 256, 256, 0, stream>>>(W1, W2, weight, Mt);
    prep_bt<<<1, D, 0, stream>>>(b1, b2, weight, bias, bt);

    hipMemsetAsync(degi, 0, NT * sizeof(int), stream);
    const int egrid = (ET + 255) / 256;                  // 4688
    degree_both<<<egrid, 256, 0, stream>>>(e_pos, e_neg, flag, degi);
    scan_pass1<<<NBLK2, SCAN_B, 0, stream>>>(degi, bsum, dinv);
    scan_pass2<<<1, 1024, 0, stream>>>(bsum);
    scan_pass3<<<NBLK2, SCAN_B, 0, stream>>>(degi, bsum, off);
    csr_fill_both<<<egrid, 256, 0, stream>>>(e_pos, e_neg, flag, off, degi, dinv, csr);

    fused_gather_gemm<<<FBLK, 512, 0, stream>>>(off, csr, xb, dinv, Mt, bt, out);
}